// Round 9
// baseline (183.084 us; speedup 1.0000x reference)
//
#include <hip/hip_runtime.h>
#include <math.h>

#define NB 4
#define C_IN 256
#define CKC 64
#define HWSZ 4096   // 64*64
#define K2 25
#define NOC2 40     // 33 output chans padded to 40 (8 groups x 5)

// workspace layout (float offsets)
#define WS_CX    0                               // cx region DEAD (fusion); first 16384 floats host wcT
#define WS_OFF   (WS_CX + NB*CKC*HWSZ)          // 1048576
#define WS_MASK  (WS_OFF + NB*8*HWSZ)           // +131072
#define WS_WT    (WS_MASK + NB*K2*HWSZ)         // +409600

#define NWT (CKC * 9 * NOC2)    // 23040
#define NWC (C_IN * CKC)        // 16384

// ---------------- Kernel D: weight prep ----------------
// wT[c][tap][oc(40)] for the 3x3 convs; wcT[c][ck] for the compressor.
__global__ void k_wt(const float* __restrict__ wk, const float* __restrict__ wo,
                     const float* __restrict__ wc,
                     float* __restrict__ wT, float* __restrict__ wcT) {
  int i = blockIdx.x * 256 + threadIdx.x;
  if (i < NWT) {
    int oc = i % NOC2;
    int r = i / NOC2;        // r = c*9 + tap
    int tap = r % 9, c = r / 9;
    float v = 0.f;
    if (oc < 8)       v = wo[(oc * CKC + c) * 9 + tap];
    else if (oc < 33) v = wk[((oc - 8) * CKC + c) * 9 + tap];
    wT[i] = v;
  } else {
    int j = i - NWT;
    if (j < NWC) {
      int c = j >> 6, ck = j & 63;
      wcT[j] = wc[ck * C_IN + c];
    }
  }
}

// ---------------- Kernel B (v7): FUSED compressor + 3x3 convs + softmax ----
// grid (64,4) x 512 thr: block = one 16x4 spatial tile.
// v7 (bank-geometry fixes, r8 postmortem: conflicts ROSE 2.36M->3.93M):
//  (1) compress-read remap: thread p owns PADDED slots q0=p, q1=min(p+60,119)
//      -> LDS reads are consecutive runs (<=2-way = free), vs r8's
//      (p/18)*20+p%18+1 mapping (3-way conflicts). Slot->halo conversion
//      (skip pad cols 0/19; slots 61-63 double-written with identical
//      values -- benign) happens once at the s_tile write.
//  (2) conv-read row stride 18->24: row groups hit banks {0,24,16,8}, each
//      16-wide window -> every bank exactly 2x = conflict-free (only
//      stride >=18 with this property mod 32; 18 gave 3-way).
//  (3) s_tile (64ck x 144 = 36.9KB) ALIASES the staging buffers: compress
//      accumulators stay in registers until after the last half-chunk, so
//      staging memory is dead when s_tile is written. Block LDS 58->36.9KB.
__global__ __launch_bounds__(512) void k_cs(const float* __restrict__ x,
    const float* __restrict__ wcT, const float* __restrict__ bc,
    const float* __restrict__ wT, const float* __restrict__ bk, const float* __restrict__ bo,
    float* __restrict__ offb, float* __restrict__ maskb) {
  __attribute__((aligned(16))) __shared__ float s_mem[9216];  // 36864B union
  // phase 1 (compress): s_xa = s_mem[0..3839], s_xb = s_mem[3840..7679]
  // phase 2 (conv):     s_tile[64][144] = s_mem[0..9215]
  // phase 3 (epilogue): s_res[NOC2*64]  = s_mem[0..2559]
  float* s_tile = s_mem;
  float* s_res  = s_mem;

  int t = threadIdx.x;
  int n = blockIdx.y;
  int tile = blockIdx.x;
  int x0 = (tile & 3) * 16, y0 = (tile >> 2) * 4;
  const float* xn = x + (size_t)n * (C_IN * HWSZ);

  // ---- hoisted float2 staging descriptors (per 32-c half-chunk) ----
  // pair e = t + it*512 over 1920 = 32c x (6 rows x 10 float2, 20-col pad);
  // dst = 2*e in [c][120] layout. halo col j (gc = x0-1+j) -> staged col j+1.
  int srcOff[4];
  unsigned vbits = 0, wbits = 0;
  #pragma unroll
  for (int it = 0; it < 4; it++) {
    int e = t + it * 512;
    int c = e / 60;
    int rem = e - c * 60;
    int row = rem / 10, pr = rem - row * 10;
    int gy = y0 - 1 + row;
    int gc0 = x0 - 2 + pr * 2;
    bool wr = (e < 1920);
    bool ok = wr & ((unsigned)gy < 64u) & ((unsigned)gc0 < 63u);  // pair fully in [0,63]
    srcOff[it] = ok ? (c * HWSZ + gy * 64 + gc0) : 0;
    vbits |= (ok ? 1u : 0u) << it;
    wbits |= (wr ? 1u : 0u) << it;
  }

  // prefetch half-chunk 0
  float2 rv[4];
  #pragma unroll
  for (int it = 0; it < 4; it++) rv[it] = *(const float2*)(xn + srcOff[it]);

  int p = t & 63;
  int g = __builtin_amdgcn_readfirstlane(t >> 6);   // ck-group 0..7, wave-uniform
  // padded-slot ownership: q0 = p (slots 0..63), q1 = p+60 (slots 60..119)
  int q1 = p + 60;
  int q1c = (q1 < 120) ? q1 : 119;                  // clamped read (write skipped)
  int r0q = p / 20,  c0q = p - r0q * 20;
  int r1q = q1c / 20, c1q = q1c - r1q * 20;
  bool val0 = (c0q >= 1) & (c0q <= 18);
  bool val1 = (q1 < 120) & (c1q >= 1) & (c1q <= 18);
  int toff0 = r0q * 24 + c0q - 1;                   // stride-24 tile offset
  int toff1 = r1q * 24 + c1q - 1;
  float a0[8], a1[8];
  #pragma unroll
  for (int i = 0; i < 8; i++) { a0[i] = bc[g * 8 + i]; a1[i] = a0[i]; }

  // prologue: buffer A <- hc0; issue hc1 loads
  float* sA = s_mem;
  float* sB = s_mem + 3840;
  #pragma unroll
  for (int it = 0; it < 4; it++)
    if (wbits & (1u << it))
      *(float2*)(&sA[2 * t + it * 1024]) =
          (vbits & (1u << it)) ? rv[it] : make_float2(0.f, 0.f);
  {
    const float* xb = xn + (size_t)32 * HWSZ;
    #pragma unroll
    for (int it = 0; it < 4; it++) rv[it] = *(const float2*)(xb + srcOff[it]);
  }
  __syncthreads();

  for (int hc = 0; hc < 8; hc++) {
    // write next half-chunk into B (overlaps FMA; B's readers passed barrier hc-1)
    if (hc < 7) {
      #pragma unroll
      for (int it = 0; it < 4; it++)
        if (wbits & (1u << it))
          *(float2*)(&sB[2 * t + it * 1024]) =
              (vbits & (1u << it)) ? rv[it] : make_float2(0.f, 0.f);
    }
    // issue hc+2 loads; latency hides under the FMA phase
    if (hc < 6) {
      const float* xb = xn + (size_t)(hc + 2) * 32 * HWSZ;
      #pragma unroll
      for (int it = 0; it < 4; it++) rv[it] = *(const float2*)(xb + srcOff[it]);
    }
    // FMA over A: 32 channels x 8 ck x 2 padded slots (consecutive-lane reads)
    const float* wbase = wcT + (hc * 32) * 64 + g * 8;
    #pragma unroll 4
    for (int c = 0; c < 32; c++) {
      float v0 = sA[c * 120 + p];
      float v1 = sA[c * 120 + q1c];
      const float* w = wbase + c * 64;
      #pragma unroll
      for (int i = 0; i < 8; i++) { a0[i] += v0 * w[i]; a1[i] += v1 * w[i]; }
    }
    __syncthreads();
    float* tmp = sA; sA = sB; sB = tmp;
  }

  // write compressed halo to s_tile [ck][6*24] (aliases dead staging mem;
  // barrier above guarantees all staging reads complete)
  if (val0) {
    #pragma unroll
    for (int i = 0; i < 8; i++) s_tile[(g * 8 + i) * 144 + toff0] = a0[i];
  }
  if (val1) {
    #pragma unroll
    for (int i = 0; i < 8; i++) s_tile[(g * 8 + i) * 144 + toff1] = a1[i];
  }
  __syncthreads();

  // ---- conv part (pipelined wa/wbuf windows; stride-24 rows) ----
  int px = p & 15, py = p >> 4;
  float acc[5];
  #pragma unroll
  for (int j = 0; j < 5; j++) acc[j] = 0.f;
  const float* wg = wT + g * 5;
  const float* tl0 = s_tile + py * 24 + px;

#define LOADWIN(dst, cidx)                                   \
  {                                                          \
    const float* tlc = tl0 + (cidx) * 144;                   \
    _Pragma("unroll")                                        \
    for (int tap = 0; tap < 9; tap++) {                      \
      int dy = tap / 3, dx = tap % 3;                        \
      dst[tap] = tlc[dy * 24 + dx];                          \
    }                                                        \
  }
#define FMAWIN(src, cidx)                                    \
  {                                                          \
    const float* wc9 = wg + (cidx) * 9 * NOC2;               \
    _Pragma("unroll")                                        \
    for (int tap = 0; tap < 9; tap++) {                      \
      float v = src[tap];                                    \
      const float* w = wc9 + tap * NOC2;                     \
      _Pragma("unroll")                                      \
      for (int j = 0; j < 5; j++) acc[j] += v * w[j];        \
    }                                                        \
  }

  float wa[9], wbuf[9];
  LOADWIN(wa, 0)
  LOADWIN(wbuf, 1)
  #pragma unroll 1
  for (int c = 0; c < CKC; c += 2) {
    FMAWIN(wa, c)
    if (c + 2 < CKC) LOADWIN(wa, c + 2)
    FMAWIN(wbuf, c + 1)
    if (c + 3 < CKC) LOADWIN(wbuf, c + 3)
  }
#undef LOADWIN
#undef FMAWIN

  // s_res aliases s_tile -> barrier between last s_tile read and first write
  __syncthreads();
  #pragma unroll
  for (int j = 0; j < 5; j++) s_res[(g * 5 + j) * 64 + p] = acc[j];
  __syncthreads();

  int hw = (y0 + py) * 64 + x0 + px;
  // offsets: 8 channels; group g writes oc = g (row index == oc)
  offb[(n * 8 + g) * HWSZ + hw] = s_res[g * 64 + p] + bo[g];
  // softmax over 25 kernel positions: threads 0..63, one pixel per lane
  if (t < 64) {
    float m[25], mx = -1e30f;
    #pragma unroll
    for (int k = 0; k < 25; k++) { m[k] = s_res[(8 + k) * 64 + p] + bk[k]; mx = fmaxf(mx, m[k]); }
    float s = 0.f;
    #pragma unroll
    for (int k = 0; k < 25; k++) { m[k] = __expf(m[k] - mx); s += m[k]; }
    float inv = 1.f / s;
    #pragma unroll
    for (int k = 0; k < 25; k++) maskb[(n * 25 + k) * HWSZ + hw] = m[k] * inv;
  }
}

// ---------------- Kernel C (v6): main CARAFE reassembly ----------------
// FROZEN at r5's 45.1us version (float2 staging, T14 prefetch, plain stores,
// no swizzle). See r5 notes: request-rate theory confirmed (62.4 -> 45.1).
__global__ __launch_bounds__(256, 4) void k_carafe(const float* __restrict__ x,
    const float* __restrict__ offb, const float* __restrict__ maskb,
    float* __restrict__ out) {
  __attribute__((aligned(16))) __shared__ float s_patch[32 * 202]; // 25856B; aliased as s_out [32][130]
  __attribute__((aligned(16))) __shared__ float s_kern[32 * 25 * 4]; // 12800B
  int t = threadIdx.x;
  int b = blockIdx.x;
  int n = b >> 8;
  int r = b & 255;
  int half = r & 1;
  int wq = (r >> 1) & 3;
  int aa = r >> 3;
  int a = aa + (aa & 16);                 // h base: bit4 == 0
  int yout = (a & 15) * 8 + wq * 2 + ((a >> 5) & 1);
  int w0 = wq * 16;
  int cbase = n * C_IN + half * 128;

  // ---- hoisted float2 staging descriptors (computed ONCE) ----
  int srcOff[13];          // channel-plane-relative src offset (pair base)
  int dstOff[13];          // LDS float index (8B aligned)
  unsigned vbits = 0;      // data-valid (in-bounds) mask
  unsigned wbits = 0;      // write-enable (e < 3200) mask
  #pragma unroll
  for (int it = 0; it < 13; it++) {
    int e = t + it * 256;
    int c = e / 100;
    int rem = e - c * 100;
    int rg = rem / 10;
    int c2 = rem - rg * 10;
    int row = (rg < 5) ? (a - 2 + rg) : (a + 9 + rg);
    int gc0 = w0 - 2 + c2 * 2;
    bool wr = (e < 3200);
    bool ok = wr & ((unsigned)row < 64u) & ((unsigned)gc0 < 64u);
    srcOff[it] = ok ? (c * HWSZ + row * 64 + gc0) : 0;
    dstOff[it] = wr ? 2 * (e + c) : 0;
    vbits |= (ok ? 1u : 0u) << it;
    wbits |= (wr ? 1u : 0u) << it;
  }

  // prefetch chunk 0 into registers (flies during phase 1)
  float2 rv[13];
  {
    const float* xn = x + (size_t)cbase * HWSZ;
    #pragma unroll
    for (int it = 0; it < 13; it++) rv[it] = *(const float2*)(xn + srcOff[it]);
  }

  // Phase 1: per-(pos,u) 25 resampled kernel weights -> LDS [p][tap][u]
  if (t < 128) {
    int p = t >> 2, u = t & 3;
    int hb = p >> 4, wl = p & 15;
    int h = a + hb * 16;
    int wcol = w0 + wl;
    float ox = offb[(n * 8 + u) * HWSZ + h * 64 + wcol];
    float oy = offb[(n * 8 + 4 + u) * HWSZ + h * 64 + wcol];
    float gx = fminf(fmaxf((float)wcol + ox, 0.f), 63.f);
    float gy = fminf(fmaxf((float)h + oy, 0.f), 63.f);
    float fx0 = floorf(gx), fy0 = floorf(gy);
    int x0 = (int)fx0, y0 = (int)fy0;
    float fx = gx - fx0, fy = gy - fy0;
    int x1 = min(x0 + 1, 63), y1 = min(y0 + 1, 63);
    float w11 = fx * fy;
    float w10 = fy - w11, w01 = fx - w11, w00 = 1.f - fx - fy + w11;
    const float* mb = maskb + n * (K2 * HWSZ);
    int i00 = y0 * 64 + x0, i01 = y0 * 64 + x1;
    int i10 = y1 * 64 + x0, i11 = y1 * 64 + x1;
    #pragma unroll 5
    for (int k = 0; k < 25; k++) {
      const float* mk = mb + k * HWSZ;
      float v = w00 * mk[i00] + w01 * mk[i01] + w10 * mk[i10] + w11 * mk[i11];
      s_kern[(p * 25 + k) * 4 + u] = v;
    }
  }

  int cl = t & 31, g = t >> 5;            // channel lane 0..31, pos-group 0..7
  int hb = g >> 2, wl0 = (g & 3) * 4;     // each group: 4 consecutive wl in one hb
  float* s_out = s_patch;                 // alias: [32][130] = 16640B <= 25856B

  for (int cc = 0; cc < 4; cc++) {
    __syncthreads();   // covers phase-1 (first iter) and staging-vs-store alias (later)
    // stage x patch from prefetched registers: 32 c x 10 rows x 20 cols
    #pragma unroll
    for (int it = 0; it < 13; it++) {
      if (wbits & (1u << it)) {
        float2 v = (vbits & (1u << it)) ? rv[it] : make_float2(0.f, 0.f);
        *(float2*)(&s_patch[dstOff[it]]) = v;   // ds_write_b64
      }
    }
    __syncthreads();
    // issue next chunk's loads NOW; latency hides under compute+store below
    if (cc < 3) {
      const float* xn = x + (size_t)(cbase + (cc + 1) * 32) * HWSZ;
      #pragma unroll
      for (int it = 0; it < 13; it++) rv[it] = *(const float2*)(xn + srcOff[it]);
    }
    // compute: thread (cl, g) -> 4 positions x 4 u; register row-cache over dy
    float acc[4][4];
    #pragma unroll
    for (int i = 0; i < 4; i++)
      acc[i][0] = acc[i][1] = acc[i][2] = acc[i][3] = 0.f;
    const float* pc = s_patch + cl * 202 + hb * 100 + wl0;
    #pragma unroll
    for (int dy = 0; dy < 5; dy++) {
      float r8[8];
      #pragma unroll
      for (int j = 0; j < 8; j++) r8[j] = pc[dy * 20 + j];
      #pragma unroll
      for (int pr = 0; pr < 4; pr++) {
        const float4* kp = (const float4*)(s_kern + (((g * 4 + pr) * 25) + dy * 5) * 4);
        #pragma unroll
        for (int dx = 0; dx < 5; dx++) {
          float f = r8[pr + dx];
          float4 k4 = kp[dx];
          acc[pr][0] += f * k4.x;
          acc[pr][1] += f * k4.y;
          acc[pr][2] += f * k4.z;
          acc[pr][3] += f * k4.w;
        }
      }
    }
    __syncthreads();
    // transpose through LDS: s_out[c][x] stride 130, x = wl*8 + u*2 + hb
    #pragma unroll
    for (int pr = 0; pr < 4; pr++) {
      int wl = wl0 + pr;
      #pragma unroll
      for (int u = 0; u < 4; u++) {
        int xo = wl * 8 + u * 2 + hb;
        s_out[cl * 130 + xo] = acc[pr][u];
      }
    }
    __syncthreads();
    // coalesced store: 32 channel-rows x 128 x at fixed yout
    float* obase = out + ((size_t)(cbase + cc * 32) * 128 + yout) * 128;
    #pragma unroll
    for (int it = 0; it < 4; it++) {
      int q2 = t + it * 256;
      int rowc = q2 >> 5;       // 0..31 (channel within chunk)
      int col4 = q2 & 31;       // float4 index within row
      const float* sp = s_out + rowc * 130 + col4 * 4;
      float4 v = make_float4(sp[0], sp[1], sp[2], sp[3]);
      *(float4*)(obase + (size_t)rowc * (128 * 128) + col4 * 4) = v;
    }
  }
}

extern "C" void kernel_launch(void* const* d_in, const int* in_sizes, int n_in,
                              void* d_out, int out_size, void* d_ws, size_t ws_size,
                              hipStream_t stream) {
  const float* x      = (const float*)d_in[0];
  const float* w_comp = (const float*)d_in[1];
  const float* b_comp = (const float*)d_in[2];
  const float* w_ker  = (const float*)d_in[3];
  const float* b_ker  = (const float*)d_in[4];
  const float* w_off  = (const float*)d_in[5];
  const float* b_off  = (const float*)d_in[6];
  float* out = (float*)d_out;
  float* ws = (float*)d_ws;
  float* offb  = ws + WS_OFF;
  float* maskb = ws + WS_MASK;
  float* wT    = ws + WS_WT;
  float* wcT   = ws + WS_CX;   // cx region is dead post-fusion; wcT lives there

  hipLaunchKernelGGL(k_wt, dim3((NWT + NWC + 255) / 256), dim3(256), 0, stream,
                     w_ker, w_off, w_comp, wT, wcT);
  hipLaunchKernelGGL(k_cs, dim3(64, 4), dim3(512), 0, stream,
                     x, wcT, b_comp, wT, b_ker, b_off, offb, maskb);
  hipLaunchKernelGGL(k_carafe, dim3(1024), dim3(256), 0, stream, x, offb, maskb, out);
}

// Round 12
// 172.841 us; speedup vs baseline: 1.0593x; 1.0593x over previous
//
#include <hip/hip_runtime.h>
#include <math.h>

#define NB 4
#define C_IN 256
#define CKC 64
#define HWSZ 4096   // 64*64
#define K2 25
#define NOC2 40     // 33 output chans padded to 40 (8 groups x 5)

// workspace layout (float offsets)
#define WS_CX    0                               // cx region DEAD (fusion); first 16384 floats host wcT
#define WS_OFF   (WS_CX + NB*CKC*HWSZ)          // 1048576
#define WS_MASK  (WS_OFF + NB*8*HWSZ)           // +131072
#define WS_WT    (WS_MASK + NB*K2*HWSZ)         // +409600

#define NWT (CKC * 9 * NOC2)    // 23040
#define NWC (C_IN * CKC)        // 16384

// ---------------- Kernel D: weight prep ----------------
// wT[c][tap][oc(40)] for the 3x3 convs; wcT[c][ck] for the compressor.
__global__ void k_wt(const float* __restrict__ wk, const float* __restrict__ wo,
                     const float* __restrict__ wc,
                     float* __restrict__ wT, float* __restrict__ wcT) {
  int i = blockIdx.x * 256 + threadIdx.x;
  if (i < NWT) {
    int oc = i % NOC2;
    int r = i / NOC2;        // r = c*9 + tap
    int tap = r % 9, c = r / 9;
    float v = 0.f;
    if (oc < 8)       v = wo[(oc * CKC + c) * 9 + tap];
    else if (oc < 33) v = wk[((oc - 8) * CKC + c) * 9 + tap];
    wT[i] = v;
  } else {
    int j = i - NWT;
    if (j < NWC) {
      int c = j >> 6, ck = j & 63;
      wcT[j] = wc[ck * C_IN + c];
    }
  }
}

// ---------------- Kernel B (v8): FUSED compress+conv+softmax, 16 waves ----
// grid (64,4) x 1024 thr: block = one 16x4 tile, 16 waves = 4 waves/SIMD.
// r9 postmortem: 3 rounds of intra-block micro-opt flat at 62-65us with
// Occ ~20% (2 waves/SIMD) -> concurrency-starved, not bank/request bound.
// v8 doubles waves/SIMD at ZERO extra FLOPs:
//  - compress: 16 waves = 8 ck-groups x 2 c-halves. Full 64-c chunks
//    double-buffered (4 barriers, was 8); chunk k FMA'd by matching half
//    while the other half stages + issues next loads (VALU/VMEM pipes
//    co-schedule across waves). Partials combined in s_tile: ch1 writes,
//    barrier, ch0 adds + bias (bias seeded in ch0 accs only).
//  - conv: c-split 0..31/32..63 across halves (per-wave chain halves);
//    s_res reduce: ch0 writes, barrier, ch1 adds.
//  - v7's bank fixes kept: padded-slot ownership (q0=p,q1=p+60), stride-24
//    s_tile rows, LDS union (s_tile aliases dead staging buffers).
// (r10/r11 failures were container-ACQUISITION infra flakes: error JSON had
//  no timing fields at all -> kernel never compiled/ran. Bounds+barrier
//  audit clean. Resubmitted unchanged, third attempt.)
__global__ __launch_bounds__(1024) void k_cs(const float* __restrict__ x,
    const float* __restrict__ wcT, const float* __restrict__ bc,
    const float* __restrict__ wT, const float* __restrict__ bk, const float* __restrict__ bo,
    float* __restrict__ offb, float* __restrict__ maskb) {
  __attribute__((aligned(16))) __shared__ float s_mem[15360];  // 61440B union
  // compress: s_A = s_mem[0..7679], s_B = s_mem[7680..15359]  (64c x 120)
  // conv:     s_tile[64][144] = s_mem[0..9215]
  // epilogue: s_res[NOC2*64]  = s_mem[0..2559]
  float* s_tile = s_mem;
  float* s_res  = s_mem;

  int t = threadIdx.x;
  int n = blockIdx.y;
  int tile = blockIdx.x;
  int x0 = (tile & 3) * 16, y0 = (tile >> 2) * 4;
  const float* xn = x + (size_t)n * (C_IN * HWSZ);

  int p = t & 63;                                   // lane
  int w = t >> 6;                                   // wave 0..15
  int g = __builtin_amdgcn_readfirstlane(w & 7);    // ck/oc-group, wave-uniform
  int ch = __builtin_amdgcn_readfirstlane(w >> 3);  // c-half, wave-uniform

  // ---- hoisted float2 staging descriptors (full 64-c chunk = 3840 f2) ----
  // pair e = t + it*1024; [c][120] layout (6 rows x 10 f2, 20-col pad from
  // x0-2); dst = 2*e. halo col j (gc = x0-1+j) -> staged col j+1.
  int srcOff[4];
  unsigned vbits = 0, wbits = 0;
  #pragma unroll
  for (int it = 0; it < 4; it++) {
    int e = t + it * 1024;
    int c = e / 60;
    int rem = e - c * 60;
    int row = rem / 10, pr = rem - row * 10;
    int gy = y0 - 1 + row;
    int gc0 = x0 - 2 + pr * 2;
    bool wr = (e < 3840);
    bool ok = wr & ((unsigned)gy < 64u) & ((unsigned)gc0 < 63u);  // pair fully in [0,63]
    srcOff[it] = ok ? (c * HWSZ + gy * 64 + gc0) : 0;
    vbits |= (ok ? 1u : 0u) << it;
    wbits |= (wr ? 1u : 0u) << it;
  }

  // padded-slot ownership: q0 = p (slots 0..63), q1 = p+60 (slots 60..119)
  int q1 = p + 60;
  int q1c = (q1 < 120) ? q1 : 119;                  // clamped read
  int r0q = p / 20,  c0q = p - r0q * 20;
  int r1q = q1c / 20, c1q = q1c - r1q * 20;
  bool val0 = (c0q >= 1) & (c0q <= 18);
  bool val1 = (q1 < 120) & (c1q >= 1) & (c1q <= 18);
  int toff0 = r0q * 24 + c0q - 1;                   // stride-24 tile offset
  int toff1 = r1q * 24 + c1q - 1;
  float a0[8], a1[8];
  #pragma unroll
  for (int i = 0; i < 8; i++) {
    float b = (ch == 0) ? bc[g * 8 + i] : 0.f;      // bias once (ch0 only)
    a0[i] = b; a1[i] = b;
  }

  // prefetch chunk 0; prologue: A <- chunk0, issue chunk1
  float2 rv[4];
  #pragma unroll
  for (int it = 0; it < 4; it++) rv[it] = *(const float2*)(xn + srcOff[it]);

  float* sA = s_mem;
  float* sB = s_mem + 7680;
  #pragma unroll
  for (int it = 0; it < 4; it++)
    if (wbits & (1u << it))
      *(float2*)(&sA[2 * t + it * 2048]) =
          (vbits & (1u << it)) ? rv[it] : make_float2(0.f, 0.f);
  {
    const float* xb = xn + (size_t)64 * HWSZ;
    #pragma unroll
    for (int it = 0; it < 4; it++) rv[it] = *(const float2*)(xb + srcOff[it]);
  }
  __syncthreads();

  for (int k = 0; k < 4; k++) {
    // stage next chunk into B (overlaps FMA of the active half)
    if (k < 3) {
      #pragma unroll
      for (int it = 0; it < 4; it++)
        if (wbits & (1u << it))
          *(float2*)(&sB[2 * t + it * 2048]) =
              (vbits & (1u << it)) ? rv[it] : make_float2(0.f, 0.f);
    }
    // issue chunk k+2 loads; latency hides under FMA phase
    if (k < 2) {
      const float* xb = xn + (size_t)(k + 2) * 64 * HWSZ;
      #pragma unroll
      for (int it = 0; it < 4; it++) rv[it] = *(const float2*)(xb + srcOff[it]);
    }
    // FMA over A by the matching c-half (wave-uniform branch)
    if ((k >> 1) == ch) {
      const float* wbase = wcT + (k * 64) * 64 + g * 8;
      #pragma unroll 4
      for (int c = 0; c < 64; c++) {
        float v0 = sA[c * 120 + p];
        float v1 = sA[c * 120 + q1c];
        const float* wp = wbase + c * 64;
        #pragma unroll
        for (int i = 0; i < 8; i++) { a0[i] += v0 * wp[i]; a1[i] += v1 * wp[i]; }
      }
    }
    __syncthreads();
    float* tmp = sA; sA = sB; sB = tmp;
  }

  // combine c-half partials into s_tile (aliases dead staging mem).
  // ch1 writes its partials to the final slots; barrier; ch0 adds its own
  // (which carry the bias). Overlap slots 60..63 have bit-identical values
  // in both owners -> duplicate RMW is value-safe.
  if (ch == 1) {
    if (val0) {
      #pragma unroll
      for (int i = 0; i < 8; i++) s_tile[(g * 8 + i) * 144 + toff0] = a0[i];
    }
    if (val1) {
      #pragma unroll
      for (int i = 0; i < 8; i++) s_tile[(g * 8 + i) * 144 + toff1] = a1[i];
    }
  }
  __syncthreads();
  if (ch == 0) {
    if (val0) {
      #pragma unroll
      for (int i = 0; i < 8; i++) {
        int idx = (g * 8 + i) * 144 + toff0;
        s_tile[idx] = s_tile[idx] + a0[i];
      }
    }
    if (val1) {
      #pragma unroll
      for (int i = 0; i < 8; i++) {
        int idx = (g * 8 + i) * 144 + toff1;
        s_tile[idx] = s_tile[idx] + a1[i];
      }
    }
  }
  __syncthreads();

  // ---- conv part: wave (g, ch) covers c in [ch*32, ch*32+32) ----
  int px = p & 15, py = p >> 4;
  float acc[5];
  #pragma unroll
  for (int j = 0; j < 5; j++) acc[j] = 0.f;
  const float* wg = wT + g * 5;
  const float* tl0 = s_tile + py * 24 + px;
  int cb = ch * 32;

#define LOADWIN(dst, cidx)                                   \
  {                                                          \
    const float* tlc = tl0 + (cidx) * 144;                   \
    _Pragma("unroll")                                        \
    for (int tap = 0; tap < 9; tap++) {                      \
      int dy = tap / 3, dx = tap % 3;                        \
      dst[tap] = tlc[dy * 24 + dx];                          \
    }                                                        \
  }
#define FMAWIN(src, cidx)                                    \
  {                                                          \
    const float* wc9 = wg + (cidx) * 9 * NOC2;               \
    _Pragma("unroll")                                        \
    for (int tap = 0; tap < 9; tap++) {                      \
      float v = src[tap];                                    \
      const float* wp = wc9 + tap * NOC2;                    \
      _Pragma("unroll")                                      \
      for (int j = 0; j < 5; j++) acc[j] += v * wp[j];       \
    }                                                        \
  }

  float wa[9], wbuf[9];
  LOADWIN(wa, cb + 0)
  LOADWIN(wbuf, cb + 1)
  #pragma unroll 1
  for (int c = 0; c < 32; c += 2) {
    FMAWIN(wa, cb + c)
    if (c + 2 < 32) LOADWIN(wa, cb + c + 2)
    FMAWIN(wbuf, cb + c + 1)
    if (c + 3 < 32) LOADWIN(wbuf, cb + c + 3)
  }
#undef LOADWIN
#undef FMAWIN

  // s_res aliases s_tile: all reads done -> ch0 writes, ch1 accumulates
  __syncthreads();
  if (ch == 0) {
    #pragma unroll
    for (int j = 0; j < 5; j++) s_res[(g * 5 + j) * 64 + p] = acc[j];
  }
  __syncthreads();
  if (ch == 1) {
    #pragma unroll
    for (int j = 0; j < 5; j++) s_res[(g * 5 + j) * 64 + p] += acc[j];
  }
  __syncthreads();

  int hw = (y0 + py) * 64 + x0 + px;
  // offsets: 8 channels; ch0 wave g writes oc = g
  if (ch == 0)
    offb[(n * 8 + g) * HWSZ + hw] = s_res[g * 64 + p] + bo[g];
  // softmax over 25 kernel positions: threads 0..63, one pixel per lane
  if (t < 64) {
    float m[25], mx = -1e30f;
    #pragma unroll
    for (int k = 0; k < 25; k++) { m[k] = s_res[(8 + k) * 64 + p] + bk[k]; mx = fmaxf(mx, m[k]); }
    float s = 0.f;
    #pragma unroll
    for (int k = 0; k < 25; k++) { m[k] = __expf(m[k] - mx); s += m[k]; }
    float inv = 1.f / s;
    #pragma unroll
    for (int k = 0; k < 25; k++) maskb[(n * 25 + k) * HWSZ + hw] = m[k] * inv;
  }
}

// ---------------- Kernel C (v6): main CARAFE reassembly ----------------
// FROZEN at r5's 45.1us version (float2 staging, T14 prefetch, plain stores,
// no swizzle). See r5 notes: request-rate theory confirmed (62.4 -> 45.1).
__global__ __launch_bounds__(256, 4) void k_carafe(const float* __restrict__ x,
    const float* __restrict__ offb, const float* __restrict__ maskb,
    float* __restrict__ out) {
  __attribute__((aligned(16))) __shared__ float s_patch[32 * 202]; // 25856B; aliased as s_out [32][130]
  __attribute__((aligned(16))) __shared__ float s_kern[32 * 25 * 4]; // 12800B
  int t = threadIdx.x;
  int b = blockIdx.x;
  int n = b >> 8;
  int r = b & 255;
  int half = r & 1;
  int wq = (r >> 1) & 3;
  int aa = r >> 3;
  int a = aa + (aa & 16);                 // h base: bit4 == 0
  int yout = (a & 15) * 8 + wq * 2 + ((a >> 5) & 1);
  int w0 = wq * 16;
  int cbase = n * C_IN + half * 128;

  // ---- hoisted float2 staging descriptors (computed ONCE) ----
  int srcOff[13];          // channel-plane-relative src offset (pair base)
  int dstOff[13];          // LDS float index (8B aligned)
  unsigned vbits = 0;      // data-valid (in-bounds) mask
  unsigned wbits = 0;      // write-enable (e < 3200) mask
  #pragma unroll
  for (int it = 0; it < 13; it++) {
    int e = t + it * 256;
    int c = e / 100;
    int rem = e - c * 100;
    int rg = rem / 10;
    int c2 = rem - rg * 10;
    int row = (rg < 5) ? (a - 2 + rg) : (a + 9 + rg);
    int gc0 = w0 - 2 + c2 * 2;
    bool wr = (e < 3200);
    bool ok = wr & ((unsigned)row < 64u) & ((unsigned)gc0 < 64u);
    srcOff[it] = ok ? (c * HWSZ + row * 64 + gc0) : 0;
    dstOff[it] = wr ? 2 * (e + c) : 0;
    vbits |= (ok ? 1u : 0u) << it;
    wbits |= (wr ? 1u : 0u) << it;
  }

  // prefetch chunk 0 into registers (flies during phase 1)
  float2 rv[13];
  {
    const float* xn = x + (size_t)cbase * HWSZ;
    #pragma unroll
    for (int it = 0; it < 13; it++) rv[it] = *(const float2*)(xn + srcOff[it]);
  }

  // Phase 1: per-(pos,u) 25 resampled kernel weights -> LDS [p][tap][u]
  if (t < 128) {
    int p = t >> 2, u = t & 3;
    int hb = p >> 4, wl = p & 15;
    int h = a + hb * 16;
    int wcol = w0 + wl;
    float ox = offb[(n * 8 + u) * HWSZ + h * 64 + wcol];
    float oy = offb[(n * 8 + 4 + u) * HWSZ + h * 64 + wcol];
    float gx = fminf(fmaxf((float)wcol + ox, 0.f), 63.f);
    float gy = fminf(fmaxf((float)h + oy, 0.f), 63.f);
    float fx0 = floorf(gx), fy0 = floorf(gy);
    int x0 = (int)fx0, y0 = (int)fy0;
    float fx = gx - fx0, fy = gy - fy0;
    int x1 = min(x0 + 1, 63), y1 = min(y0 + 1, 63);
    float w11 = fx * fy;
    float w10 = fy - w11, w01 = fx - w11, w00 = 1.f - fx - fy + w11;
    const float* mb = maskb + n * (K2 * HWSZ);
    int i00 = y0 * 64 + x0, i01 = y0 * 64 + x1;
    int i10 = y1 * 64 + x0, i11 = y1 * 64 + x1;
    #pragma unroll 5
    for (int k = 0; k < 25; k++) {
      const float* mk = mb + k * HWSZ;
      float v = w00 * mk[i00] + w01 * mk[i01] + w10 * mk[i10] + w11 * mk[i11];
      s_kern[(p * 25 + k) * 4 + u] = v;
    }
  }

  int cl = t & 31, g = t >> 5;            // channel lane 0..31, pos-group 0..7
  int hb = g >> 2, wl0 = (g & 3) * 4;     // each group: 4 consecutive wl in one hb
  float* s_out = s_patch;                 // alias: [32][130] = 16640B <= 25856B

  for (int cc = 0; cc < 4; cc++) {
    __syncthreads();   // covers phase-1 (first iter) and staging-vs-store alias (later)
    // stage x patch from prefetched registers: 32 c x 10 rows x 20 cols
    #pragma unroll
    for (int it = 0; it < 13; it++) {
      if (wbits & (1u << it)) {
        float2 v = (vbits & (1u << it)) ? rv[it] : make_float2(0.f, 0.f);
        *(float2*)(&s_patch[dstOff[it]]) = v;   // ds_write_b64
      }
    }
    __syncthreads();
    // issue next chunk's loads NOW; latency hides under compute+store below
    if (cc < 3) {
      const float* xn = x + (size_t)(cbase + (cc + 1) * 32) * HWSZ;
      #pragma unroll
      for (int it = 0; it < 13; it++) rv[it] = *(const float2*)(xn + srcOff[it]);
    }
    // compute: thread (cl, g) -> 4 positions x 4 u; register row-cache over dy
    float acc[4][4];
    #pragma unroll
    for (int i = 0; i < 4; i++)
      acc[i][0] = acc[i][1] = acc[i][2] = acc[i][3] = 0.f;
    const float* pc = s_patch + cl * 202 + hb * 100 + wl0;
    #pragma unroll
    for (int dy = 0; dy < 5; dy++) {
      float r8[8];
      #pragma unroll
      for (int j = 0; j < 8; j++) r8[j] = pc[dy * 20 + j];
      #pragma unroll
      for (int pr = 0; pr < 4; pr++) {
        const float4* kp = (const float4*)(s_kern + (((g * 4 + pr) * 25) + dy * 5) * 4);
        #pragma unroll
        for (int dx = 0; dx < 5; dx++) {
          float f = r8[pr + dx];
          float4 k4 = kp[dx];
          acc[pr][0] += f * k4.x;
          acc[pr][1] += f * k4.y;
          acc[pr][2] += f * k4.z;
          acc[pr][3] += f * k4.w;
        }
      }
    }
    __syncthreads();
    // transpose through LDS: s_out[c][x] stride 130, x = wl*8 + u*2 + hb
    #pragma unroll
    for (int pr = 0; pr < 4; pr++) {
      int wl = wl0 + pr;
      #pragma unroll
      for (int u = 0; u < 4; u++) {
        int xo = wl * 8 + u * 2 + hb;
        s_out[cl * 130 + xo] = acc[pr][u];
      }
    }
    __syncthreads();
    // coalesced store: 32 channel-rows x 128 x at fixed yout
    float* obase = out + ((size_t)(cbase + cc * 32) * 128 + yout) * 128;
    #pragma unroll
    for (int it = 0; it < 4; it++) {
      int q2 = t + it * 256;
      int rowc = q2 >> 5;       // 0..31 (channel within chunk)
      int col4 = q2 & 31;       // float4 index within row
      const float* sp = s_out + rowc * 130 + col4 * 4;
      float4 v = make_float4(sp[0], sp[1], sp[2], sp[3]);
      *(float4*)(obase + (size_t)rowc * (128 * 128) + col4 * 4) = v;
    }
  }
}

extern "C" void kernel_launch(void* const* d_in, const int* in_sizes, int n_in,
                              void* d_out, int out_size, void* d_ws, size_t ws_size,
                              hipStream_t stream) {
  const float* x      = (const float*)d_in[0];
  const float* w_comp = (const float*)d_in[1];
  const float* b_comp = (const float*)d_in[2];
  const float* w_ker  = (const float*)d_in[3];
  const float* b_ker  = (const float*)d_in[4];
  const float* w_off  = (const float*)d_in[5];
  const float* b_off  = (const float*)d_in[6];
  float* out = (float*)d_out;
  float* ws = (float*)d_ws;
  float* offb  = ws + WS_OFF;
  float* maskb = ws + WS_MASK;
  float* wT    = ws + WS_WT;
  float* wcT   = ws + WS_CX;   // cx region is dead post-fusion; wcT lives there

  hipLaunchKernelGGL(k_wt, dim3((NWT + NWC + 255) / 256), dim3(256), 0, stream,
                     w_ker, w_off, w_comp, wT, wcT);
  hipLaunchKernelGGL(k_cs, dim3(64, 4), dim3(1024), 0, stream,
                     x, wcT, b_comp, wT, b_ker, b_off, offb, maskb);
  hipLaunchKernelGGL(k_carafe, dim3(1024), dim3(256), 0, stream, x, offb, maskb, out);
}